// Round 2
// baseline (1248.045 us; speedup 1.0000x reference)
//
#include <hip/hip_runtime.h>

typedef unsigned short u16;
typedef unsigned int   u32;
typedef __attribute__((ext_vector_type(8))) __bf16 bf16x8;
typedef __attribute__((ext_vector_type(4))) float  f32x4;

#define B_   32
#define T_   64
#define S_   128
#define E_   256
#define H_   512
#define ENC_ 512
#define V_   32000

__device__ __forceinline__ float b2f(u16 u) {
  union { u32 i; float f; } v; v.i = ((u32)u) << 16; return v.f;
}
__device__ __forceinline__ u16 f2b(float f) {
  union { float f; u32 i; } v; v.f = f;
  u32 r = (v.i + 0x7fffu + ((v.i >> 16) & 1u)) >> 16;
  return (u16)r;
}
__device__ __forceinline__ float sigm(float x) { return 1.f / (1.f + __expf(-x)); }

// async global->LDS, 16B per lane. LDS dest must be wave-uniform base + lane*16.
__device__ __forceinline__ void async_ld16(const void* g, void* l) {
  __builtin_amdgcn_global_load_lds((const __attribute__((address_space(1))) u32*)g,
                                   (__attribute__((address_space(3))) u32*)l,
                                   16, 0, 0);
}

// ---------------------------------------------------------------------------
// f32 -> bf16 convert, 4 elems/thread (float4 in, 8B out). n % 4 == 0.
// ---------------------------------------------------------------------------
__global__ __launch_bounds__(256) void k_cvt(const float* __restrict__ src,
                                             u16* __restrict__ dst, int n4) {
  int i = blockIdx.x * 256 + threadIdx.x;
  if (i < n4) {
    float4 v = ((const float4*)src)[i];
    ushort4 o;
    o.x = f2b(v.x); o.y = f2b(v.y); o.z = f2b(v.z); o.w = f2b(v.w);
    ((ushort4*)dst)[i] = o;
  }
}

// ---------------------------------------------------------------------------
// Generic bf16 B^T GEMM (m97-style): C[M,N] = A[M,K] * B[N,K]^T (+bias1+bias2)
// 128x128 tile, BK=64, 4 waves (2x2 of 64x64), 16x16x32 bf16 MFMA.
// M%128==0, N%128==0, K%64==0 guaranteed by caller. Biases are f32.
// ---------------------------------------------------------------------------
template <typename OUT_T>
__global__ __launch_bounds__(256) void gemm_bt(
    const u16* __restrict__ A, int lda,
    const u16* __restrict__ B, int ldb,
    OUT_T* __restrict__ C, int ldc, int K,
    const float* __restrict__ bias1, const float* __restrict__ bias2) {
  __shared__ __align__(16) u16 As[128 * 64];
  __shared__ __align__(16) u16 Bs[128 * 64];

  const int tid  = threadIdx.x;
  const int m0   = blockIdx.x * 128;
  const int n0   = blockIdx.y * 128;
  const int wave = tid >> 6, lane = tid & 63;
  const int mw = (wave >> 1) * 64, nw = (wave & 1) * 64;
  const int lr = lane & 15, lq = lane >> 4;

  f32x4 acc[4][4];
#pragma unroll
  for (int i = 0; i < 4; ++i)
#pragma unroll
    for (int j = 0; j < 4; ++j) acc[i][j] = (f32x4){0.f, 0.f, 0.f, 0.f};

  for (int k0 = 0; k0 < K; k0 += 64) {
#pragma unroll
    for (int it = 0; it < 4; ++it) {
      int chunk = it * 256 + tid;       // 0..1023 16B-chunks
      int row = chunk >> 3;
      int kc  = (chunk & 7) << 3;
      async_ld16(&A[(size_t)(m0 + row) * lda + k0 + kc], &As[chunk << 3]);
    }
#pragma unroll
    for (int it = 0; it < 4; ++it) {
      int chunk = it * 256 + tid;
      int row = chunk >> 3;
      int kc  = (chunk & 7) << 3;
      async_ld16(&B[(size_t)(n0 + row) * ldb + k0 + kc], &Bs[chunk << 3]);
    }
    __syncthreads();  // drains vmcnt (global_load_lds) + barrier
#pragma unroll
    for (int kk = 0; kk < 2; ++kk) {
      bf16x8 af[4], bf[4];
#pragma unroll
      for (int i = 0; i < 4; ++i)
        af[i] = *(const bf16x8*)&As[(mw + i * 16 + lr) * 64 + kk * 32 + lq * 8];
#pragma unroll
      for (int j = 0; j < 4; ++j)
        bf[j] = *(const bf16x8*)&Bs[(nw + j * 16 + lr) * 64 + kk * 32 + lq * 8];
#pragma unroll
      for (int i = 0; i < 4; ++i)
#pragma unroll
        for (int j = 0; j < 4; ++j)
          acc[i][j] = __builtin_amdgcn_mfma_f32_16x16x32_bf16(af[i], bf[j], acc[i][j], 0, 0, 0);
    }
    __syncthreads();
  }

#pragma unroll
  for (int j = 0; j < 4; ++j) {
    int n = n0 + nw + j * 16 + lr;
    float bs = 0.f;
    if (bias1) bs += bias1[n];
    if (bias2) bs += bias2[n];
#pragma unroll
    for (int i = 0; i < 4; ++i) {
#pragma unroll
      for (int r = 0; r < 4; ++r) {
        int m = m0 + mw + i * 16 + lq * 4 + r;
        float v = acc[i][j][r] + bs;
        if constexpr (sizeof(OUT_T) == 2)
          C[(size_t)m * ldc + n] = (OUT_T)f2b(v);
        else
          C[(size_t)m * ldc + n] = v;
      }
    }
  }
}

// ---------------------------------------------------------------------------
// Embedding gather + f32->bf16: emb[bt][e] = bf16(table[tok[bt]][e]).
// 131072 threads: row = id>>6, 64 chunks of 4 elems.
// ---------------------------------------------------------------------------
__global__ __launch_bounds__(256) void k_embed(const int* __restrict__ toks,
                                               const float* __restrict__ table,
                                               u16* __restrict__ emb) {
  int id  = blockIdx.x * 256 + threadIdx.x;
  int row = id >> 6;
  int c4  = (id & 63) << 2;
  int tok = toks[row];
  float4 v = *(const float4*)&table[(size_t)tok * E_ + c4];
  ushort4 o;
  o.x = f2b(v.x); o.y = f2b(v.y); o.z = f2b(v.z); o.w = f2b(v.w);
  *(ushort4*)&emb[(size_t)row * E_ + c4] = o;
}

// ---------------------------------------------------------------------------
// Wa transpose + convert: WaT[e][h] = bf16(Wa[h][e])  (512x512).
// ---------------------------------------------------------------------------
__global__ __launch_bounds__(256) void k_transpose(const float* __restrict__ Wa,
                                                   u16* __restrict__ WaT) {
  __shared__ float tle[32][33];
  int bx = blockIdx.x * 32;  // h
  int by = blockIdx.y * 32;  // e
  int tid = threadIdx.x;
  for (int i = tid; i < 1024; i += 256) {
    int r = i >> 5, c = i & 31;
    tle[r][c] = Wa[(size_t)(bx + r) * ENC_ + by + c];
  }
  __syncthreads();
  for (int i = tid; i < 1024; i += 256) {
    int r = i >> 5, c = i & 31;
    WaT[(size_t)(by + r) * H_ + bx + c] = f2b(tle[c][r]);
  }
}

// ---------------------------------------------------------------------------
// Sequential LSTM core. 64 persistent blocks (<=256 CUs -> all co-resident).
// Block n owns h-indices [8n,8n+8) => W_hh rows {g*512+8n+j} held in regs.
// Per step: gates = gates_pre + H @ W_hh^T via 16x16x32 MFMA, pointwise,
// publish h_t, device-scope barrier (per-step counter, no reset needed).
// Hbuf slot 0 = bf16(h0); slot t+1 = h_t.
// ---------------------------------------------------------------------------
__global__ __launch_bounds__(256) void k_lstm(
    const u16* __restrict__ Whh,   // bf16 [2048][512]
    const float* __restrict__ gp,  // gates_pre [B*T][2048]
    const float* __restrict__ c0,  // [32][512] f32
    u16* __restrict__ Hbuf,        // [65][32][512] bf16
    u16* __restrict__ hc,          // [B*T][1024] bf16, cols 0..511 = h
    int* __restrict__ bar) {       // [64] zeroed counters
  const int nblk = gridDim.x;  // 64
  const int blk  = blockIdx.x;
  const int tid  = threadIdx.x;
  const int wave = tid >> 6, lane = tid & 63;
  const int mi = wave >> 1, ni = wave & 1;
  const int lr = lane & 15, lq = lane >> 4;

  // B-operand (W_hh rows) resident in registers for whole kernel.
  const int p    = ni * 16 + lr;                          // col within 32-set
  const int grow = (p >> 3) * H_ + blk * 8 + (p & 7);     // global gate row
  bf16x8 bfr[16];
#pragma unroll
  for (int ks = 0; ks < 16; ++ks)
    bfr[ks] = *(const bf16x8*)&Whh[(size_t)grow * H_ + ks * 32 + lq * 8];

  // c-state: thread (b=tid>>3, j=tid&7) owns c[b][blk*8+j] in a register.
  const int pb = tid >> 3, pj = tid & 7;
  const int hidx = blk * 8 + pj;
  float c = c0[pb * H_ + hidx];

  __shared__ float G[32][33];  // +1 pad: avoid bank conflicts on col access

  for (int t = 0; t < T_; ++t) {
    const u16* Hsrc = Hbuf + (size_t)t * (B_ * H_);
    f32x4 acc = (f32x4){0.f, 0.f, 0.f, 0.f};
    const int am = mi * 16 + lr;
#pragma unroll
    for (int ks = 0; ks < 16; ++ks) {
      bf16x8 a = *(const bf16x8*)&Hsrc[am * H_ + ks * 32 + lq * 8];
      acc = __builtin_amdgcn_mfma_f32_16x16x32_bf16(a, bfr[ks], acc, 0, 0, 0);
    }
#pragma unroll
    for (int r = 0; r < 4; ++r) {
      int b = mi * 16 + lq * 4 + r;
      G[b][p] = acc[r] + gp[(size_t)(b * T_ + t) * 2048 + grow];
    }
    __syncthreads();
    // pointwise: i,f,g,o at cols j, 8+j, 16+j, 24+j of the 32-set
    float gi = G[pb][pj], gf = G[pb][8 + pj], gg = G[pb][16 + pj], go = G[pb][24 + pj];
    c = sigm(gf) * c + sigm(gi) * tanhf(gg);
    float h = sigm(go) * tanhf(c);
    u16 hb = f2b(h);
    Hbuf[(size_t)(t + 1) * (B_ * H_) + pb * H_ + hidx] = hb;
    hc[(size_t)(pb * T_ + t) * 1024 + hidx]            = hb;

    if (t < T_ - 1) {
      __threadfence();   // device-scope release of h stores
      __syncthreads();
      if (tid == 0) {
        __hip_atomic_fetch_add(&bar[t], 1, __ATOMIC_RELEASE, __HIP_MEMORY_SCOPE_AGENT);
        while (__hip_atomic_load(&bar[t], __ATOMIC_ACQUIRE, __HIP_MEMORY_SCOPE_AGENT) < nblk) {
        }
      }
      __syncthreads();   // also protects LDS G reuse
    }
  }
}

// ---------------------------------------------------------------------------
// Attention: one block per (b,t). scores = q . enc, mask, softmax, ctx.
// enc here is the bf16 copy. Writes ctx (bf16) into hc cols 512..1023.
// ---------------------------------------------------------------------------
__global__ __launch_bounds__(256) void k_attn(
    const u16* __restrict__ q,    // bf16 [B*T][512]
    const u16* __restrict__ enc,  // bf16 [B][S][512]
    const int* __restrict__ lens, // [B]
    u16* __restrict__ hc) {       // bf16 [B*T][1024]
  const int bt = blockIdx.x;
  const int b  = bt >> 6;  // bt = b*T + t
  const int tid = threadIdx.x;
  const int len = lens[b];

  __shared__ float qs[512];
  __shared__ float sc[128];
  __shared__ float red2[256];
  __shared__ float sred[2];

  for (int i = tid; i < 512; i += 256) qs[i] = b2f(q[(size_t)bt * 512 + i]);
  __syncthreads();

  // scores: thread (s = tid&127, half = tid>>7) sums 256 of 512 k's
  {
    int s = tid & 127, half = tid >> 7;
    const u16* er = &enc[((size_t)b * S_ + s) * 512 + half * 256];
    const float* qb = &qs[half * 256];
    float a = 0.f;
#pragma unroll 4
    for (int k = 0; k < 256; k += 8) {
      uint4 raw = *(const uint4*)&er[k];
      u32 w0 = raw.x, w1 = raw.y, w2 = raw.z, w3 = raw.w;
      union { u32 i; float f; } lo, hi;
      lo.i = w0 << 16;          a += lo.f * qb[k + 0];
      hi.i = w0 & 0xffff0000u;  a += hi.f * qb[k + 1];
      lo.i = w1 << 16;          a += lo.f * qb[k + 2];
      hi.i = w1 & 0xffff0000u;  a += hi.f * qb[k + 3];
      lo.i = w2 << 16;          a += lo.f * qb[k + 4];
      hi.i = w2 & 0xffff0000u;  a += hi.f * qb[k + 5];
      lo.i = w3 << 16;          a += lo.f * qb[k + 6];
      hi.i = w3 & 0xffff0000u;  a += hi.f * qb[k + 7];
    }
    red2[tid] = a;
  }
  __syncthreads();
  if (tid < 128) {
    float v = red2[tid] + red2[tid + 128];
    sc[tid] = (tid < len) ? v : -1e30f;
  }
  __syncthreads();
  if (tid < 64) {
    float m = fmaxf(sc[tid], sc[tid + 64]);
#pragma unroll
    for (int o = 32; o > 0; o >>= 1) m = fmaxf(m, __shfl_down(m, o));
    if (tid == 0) sred[0] = m;
  }
  __syncthreads();
  float mx = sred[0];
  if (tid < 128) sc[tid] = __expf(sc[tid] - mx);
  __syncthreads();
  if (tid < 64) {
    float s2 = sc[tid] + sc[tid + 64];
#pragma unroll
    for (int o = 32; o > 0; o >>= 1) s2 += __shfl_down(s2, o);
    if (tid == 0) sred[1] = s2;
  }
  __syncthreads();
  float inv = 1.0f / sred[1];

  // ctx[e] = sum_s att[s] * enc[b][s][e]; thread handles e = tid, tid+256
  float a0 = 0.f, a1 = 0.f;
  for (int s = 0; s < S_; ++s) {
    float at = sc[s];
    const u16* er = &enc[((size_t)b * S_ + s) * 512];
    a0 += at * b2f(er[tid]);
    a1 += at * b2f(er[tid + 256]);
  }
  hc[(size_t)bt * 1024 + 512 + tid]       = f2b(a0 * inv);
  hc[(size_t)bt * 1024 + 512 + tid + 256] = f2b(a1 * inv);
}

// ---------------------------------------------------------------------------
extern "C" void kernel_launch(void* const* d_in, const int* in_sizes, int n_in,
                              void* d_out, int out_size, void* d_ws, size_t ws_size,
                              hipStream_t stream) {
  const int*   toks  = (const int*)d_in[0];
  const float* enc   = (const float*)d_in[1];
  const int*   lens  = (const int*)d_in[2];
  const float* h0    = (const float*)d_in[3];
  const float* c0    = (const float*)d_in[4];
  const float* table = (const float*)d_in[5];
  const float* W_ih  = (const float*)d_in[6];
  const float* W_hh  = (const float*)d_in[7];
  const float* b_ih  = (const float*)d_in[8];
  const float* b_hh  = (const float*)d_in[9];
  const float* Wa    = (const float*)d_in[10];
  const float* Wc_w  = (const float*)d_in[11];
  const float* Wc_b  = (const float*)d_in[12];
  const float* Wo_w  = (const float*)d_in[13];
  const float* Wo_b  = (const float*)d_in[14];
  float* out = (float*)d_out;

  char* ws = (char*)d_ws;
  size_t off = 0;
  auto alloc = [&](size_t bytes) {
    void* pp = ws + off;
    off += (bytes + 255) & ~(size_t)255;
    return pp;
  };
  int*   bar   = (int*)alloc(64 * sizeof(int));
  float* gp    = (float*)alloc((size_t)B_ * T_ * 2048 * 4);    // 16.8 MB
  u16*   emb   = (u16*)alloc((size_t)B_ * T_ * E_ * 2);        // 1 MB
  u16*   Hbuf  = (u16*)alloc((size_t)(T_ + 1) * B_ * H_ * 2);  // 2.1 MB
  u16*   hc    = (u16*)alloc((size_t)B_ * T_ * 1024 * 2);      // 4 MB
  u16*   q     = (u16*)alloc((size_t)B_ * T_ * ENC_ * 2);      // 2 MB
  u16*   WaT   = (u16*)alloc((size_t)ENC_ * H_ * 2);           // 0.5 MB
  u16*   ho    = (u16*)alloc((size_t)B_ * T_ * H_ * 2);        // 2 MB
  u16*   Wihb  = (u16*)alloc((size_t)2048 * E_ * 2);           // 1 MB
  u16*   Whhb  = (u16*)alloc((size_t)2048 * H_ * 2);           // 2 MB
  u16*   Wcwb  = (u16*)alloc((size_t)H_ * 1024 * 2);           // 1 MB
  u16*   Wowb  = (u16*)alloc((size_t)V_ * H_ * 2);             // 32.8 MB
  u16*   encb  = (u16*)alloc((size_t)B_ * S_ * ENC_ * 2);      // 4.2 MB
  (void)in_sizes; (void)n_in; (void)out_size; (void)ws_size;

  hipMemsetAsync(bar, 0, 64 * sizeof(int), stream);

  // 0. dtype converts (f32 -> bf16)
  k_cvt<<<(2048 * E_ / 4 + 255) / 256, 256, 0, stream>>>(W_ih, Wihb, 2048 * E_ / 4);
  k_cvt<<<(2048 * H_ / 4 + 255) / 256, 256, 0, stream>>>(W_hh, Whhb, 2048 * H_ / 4);
  k_cvt<<<(H_ * 1024 / 4 + 255) / 256, 256, 0, stream>>>(Wc_w, Wcwb, H_ * 1024 / 4);
  k_cvt<<<(V_ * H_ / 4 + 255) / 256, 256, 0, stream>>>(Wo_w, Wowb, V_ * H_ / 4);
  k_cvt<<<(B_ * S_ * ENC_ / 4 + 255) / 256, 256, 0, stream>>>(enc, encb, B_ * S_ * ENC_ / 4);
  k_cvt<<<(B_ * H_ / 4 + 255) / 256, 256, 0, stream>>>(h0, Hbuf, B_ * H_ / 4);  // slot 0
  // 1. embedding gather (+convert)
  k_embed<<<512, 256, 0, stream>>>(toks, table, emb);
  // 2. gates_pre = emb @ W_ih^T + b_ih + b_hh   [2048 x 2048], K=256, f32 out
  gemm_bt<float><<<dim3(16, 16), 256, 0, stream>>>(emb, E_, Wihb, E_, gp, 2048, E_, b_ih, b_hh);
  // 3. WaT = Wa^T (bf16)
  k_transpose<<<dim3(16, 16), 256, 0, stream>>>(Wa, WaT);
  // 4. sequential LSTM core -> h into hc[:, 0:512] and Hbuf slots 1..64
  k_lstm<<<64, 256, 0, stream>>>(Whhb, gp, c0, Hbuf, hc, bar);
  // 5. q = h @ Wa  == hc[:,0:512] @ WaT^T   [2048 x 512], K=512, bf16 out
  gemm_bt<u16><<<dim3(16, 4), 256, 0, stream>>>(hc, 1024, WaT, H_, q, ENC_, H_, nullptr, nullptr);
  // 6. attention -> ctx into hc[:, 512:1024]
  k_attn<<<B_ * T_, 256, 0, stream>>>(q, encb, lens, hc);
  // 7. ho = [h,ctx] @ Wc_w^T + Wc_b   [2048 x 512], K=1024
  gemm_bt<u16><<<dim3(16, 4), 256, 0, stream>>>(hc, 1024, Wcwb, 1024, ho, H_, 1024, Wc_b, nullptr);
  // 8. logits = ho @ Wo^T + Wo_b -> d_out (f32)   [2048 x 32000], K=512
  gemm_bt<float><<<dim3(16, 250), 256, 0, stream>>>(ho, H_, Wowb, H_, out, V_, H_, Wo_b, nullptr);
}

// Round 3
// 1003.697 us; speedup vs baseline: 1.2434x; 1.2434x over previous
//
#include <hip/hip_runtime.h>

typedef unsigned short u16;
typedef unsigned int   u32;
typedef __attribute__((ext_vector_type(8))) __bf16 bf16x8;
typedef __attribute__((ext_vector_type(4))) float  f32x4;

#define B_   32
#define T_   64
#define S_   128
#define E_   256
#define H_   512
#define ENC_ 512
#define V_   32000

__device__ __forceinline__ float b2f(u16 u) {
  union { u32 i; float f; } v; v.i = ((u32)u) << 16; return v.f;
}
__device__ __forceinline__ u16 f2b(float f) {
  union { float f; u32 i; } v; v.f = f;
  u32 r = (v.i + 0x7fffu + ((v.i >> 16) & 1u)) >> 16;
  return (u16)r;
}
__device__ __forceinline__ float sigm(float x) { return 1.f / (1.f + __expf(-x)); }

// async global->LDS, 16B per lane. LDS dest must be wave-uniform base + lane*16.
__device__ __forceinline__ void async_ld16(const void* g, void* l) {
  __builtin_amdgcn_global_load_lds((const __attribute__((address_space(1))) u32*)g,
                                   (__attribute__((address_space(3))) u32*)l,
                                   16, 0, 0);
}

// ---------------------------------------------------------------------------
// f32 -> bf16 convert, 4 elems/thread (float4 in, 8B out). n % 4 == 0.
// ---------------------------------------------------------------------------
__global__ __launch_bounds__(256) void k_cvt(const float* __restrict__ src,
                                             u16* __restrict__ dst, int n4) {
  int i = blockIdx.x * 256 + threadIdx.x;
  if (i < n4) {
    float4 v = ((const float4*)src)[i];
    ushort4 o;
    o.x = f2b(v.x); o.y = f2b(v.y); o.z = f2b(v.z); o.w = f2b(v.w);
    ((ushort4*)dst)[i] = o;
  }
}

// ---------------------------------------------------------------------------
// Generic bf16 B^T GEMM (m97-style): C[M,N] = A[M,K] * B[N,K]^T (+bias1+bias2)
// 128x128 tile, BK=64, 4 waves (2x2 of 64x64), 16x16x32 bf16 MFMA.
// M%128==0, N%128==0, K%64==0 guaranteed by caller. Biases are f32.
// ---------------------------------------------------------------------------
template <typename OUT_T>
__global__ __launch_bounds__(256) void gemm_bt(
    const u16* __restrict__ A, int lda,
    const u16* __restrict__ B, int ldb,
    OUT_T* __restrict__ C, int ldc, int K,
    const float* __restrict__ bias1, const float* __restrict__ bias2) {
  __shared__ __align__(16) u16 As[128 * 64];
  __shared__ __align__(16) u16 Bs[128 * 64];

  const int tid  = threadIdx.x;
  const int m0   = blockIdx.x * 128;
  const int n0   = blockIdx.y * 128;
  const int wave = tid >> 6, lane = tid & 63;
  const int mw = (wave >> 1) * 64, nw = (wave & 1) * 64;
  const int lr = lane & 15, lq = lane >> 4;

  f32x4 acc[4][4];
#pragma unroll
  for (int i = 0; i < 4; ++i)
#pragma unroll
    for (int j = 0; j < 4; ++j) acc[i][j] = (f32x4){0.f, 0.f, 0.f, 0.f};

  for (int k0 = 0; k0 < K; k0 += 64) {
#pragma unroll
    for (int it = 0; it < 4; ++it) {
      int chunk = it * 256 + tid;       // 0..1023 16B-chunks
      int row = chunk >> 3;
      int kc  = (chunk & 7) << 3;
      async_ld16(&A[(size_t)(m0 + row) * lda + k0 + kc], &As[chunk << 3]);
    }
#pragma unroll
    for (int it = 0; it < 4; ++it) {
      int chunk = it * 256 + tid;
      int row = chunk >> 3;
      int kc  = (chunk & 7) << 3;
      async_ld16(&B[(size_t)(n0 + row) * ldb + k0 + kc], &Bs[chunk << 3]);
    }
    __syncthreads();  // drains vmcnt (global_load_lds) + barrier
#pragma unroll
    for (int kk = 0; kk < 2; ++kk) {
      bf16x8 af[4], bf[4];
#pragma unroll
      for (int i = 0; i < 4; ++i)
        af[i] = *(const bf16x8*)&As[(mw + i * 16 + lr) * 64 + kk * 32 + lq * 8];
#pragma unroll
      for (int j = 0; j < 4; ++j)
        bf[j] = *(const bf16x8*)&Bs[(nw + j * 16 + lr) * 64 + kk * 32 + lq * 8];
#pragma unroll
      for (int i = 0; i < 4; ++i)
#pragma unroll
        for (int j = 0; j < 4; ++j)
          acc[i][j] = __builtin_amdgcn_mfma_f32_16x16x32_bf16(af[i], bf[j], acc[i][j], 0, 0, 0);
    }
    __syncthreads();
  }

#pragma unroll
  for (int j = 0; j < 4; ++j) {
    int n = n0 + nw + j * 16 + lr;
    float bs = 0.f;
    if (bias1) bs += bias1[n];
    if (bias2) bs += bias2[n];
#pragma unroll
    for (int i = 0; i < 4; ++i) {
#pragma unroll
      for (int r = 0; r < 4; ++r) {
        int m = m0 + mw + i * 16 + lq * 4 + r;
        float v = acc[i][j][r] + bs;
        if constexpr (sizeof(OUT_T) == 2)
          C[(size_t)m * ldc + n] = (OUT_T)f2b(v);
        else
          C[(size_t)m * ldc + n] = v;
      }
    }
  }
}

// ---------------------------------------------------------------------------
// Embedding gather + f32->bf16: emb[bt][e] = bf16(table[tok[bt]][e]).
// ---------------------------------------------------------------------------
__global__ __launch_bounds__(256) void k_embed(const int* __restrict__ toks,
                                               const float* __restrict__ table,
                                               u16* __restrict__ emb) {
  int id  = blockIdx.x * 256 + threadIdx.x;
  int row = id >> 6;
  int c4  = (id & 63) << 2;
  int tok = toks[row];
  float4 v = *(const float4*)&table[(size_t)tok * E_ + c4];
  ushort4 o;
  o.x = f2b(v.x); o.y = f2b(v.y); o.z = f2b(v.z); o.w = f2b(v.w);
  *(ushort4*)&emb[(size_t)row * E_ + c4] = o;
}

// ---------------------------------------------------------------------------
// Wa transpose + convert: WaT[e][h] = bf16(Wa[h][e])  (512x512).
// ---------------------------------------------------------------------------
__global__ __launch_bounds__(256) void k_transpose(const float* __restrict__ Wa,
                                                   u16* __restrict__ WaT) {
  __shared__ float tle[32][33];
  int bx = blockIdx.x * 32;  // h
  int by = blockIdx.y * 32;  // e
  int tid = threadIdx.x;
  for (int i = tid; i < 1024; i += 256) {
    int r = i >> 5, c = i & 31;
    tle[r][c] = Wa[(size_t)(bx + r) * ENC_ + by + c];
  }
  __syncthreads();
  for (int i = tid; i < 1024; i += 256) {
    int r = i >> 5, c = i & 31;
    WaT[(size_t)(by + r) * H_ + bx + c] = f2b(tle[c][r]);
  }
}

// ---------------------------------------------------------------------------
// Sequential LSTM core. 64 persistent blocks. Block n owns h-indices
// [8n,8n+8) => W_hh rows {g*512+8n+j} held in regs. Per step:
//   - h_{t-1} staged LDS<-global once (global_load_lds x16B)
//   - gates = gates_pre + H @ W_hh^T via 16x16x32 MFMA
//   - pointwise, publish h_t
//   - cross-block barrier: RELAXED agent spin + ONE release/acquire fence
//     per step (per-poll ACQUIRE was emitting buffer_inv each iteration ->
//     L2 wiped dozens of times/step -> 10.8us/step in round 2).
//   - gp for t+1 prefetched into regs before the barrier (gp is constant,
//     so coherence-safe; loads complete during the spin).
// Hbuf slot 0 = bf16(h0); slot t+1 = h_t.
// ---------------------------------------------------------------------------
__global__ __launch_bounds__(256) void k_lstm(
    const u16* __restrict__ Whh,   // bf16 [2048][512]
    const float* __restrict__ gp,  // gates_pre [B*T][2048]
    const float* __restrict__ c0,  // [32][512] f32
    u16* __restrict__ Hbuf,        // [65][32][512] bf16
    u16* __restrict__ hc,          // [B*T][1024] bf16, cols 0..511 = h
    int* __restrict__ bar) {       // [64] zeroed counters
  const int nblk = gridDim.x;  // 64
  const int blk  = blockIdx.x;
  const int tid  = threadIdx.x;
  const int wave = tid >> 6, lane = tid & 63;
  const int mi = wave >> 1, ni = wave & 1;
  const int lr = lane & 15, lq = lane >> 4;

  // B-operand (W_hh rows) resident in registers for whole kernel.
  const int p    = ni * 16 + lr;                          // col within 32-set
  const int grow = (p >> 3) * H_ + blk * 8 + (p & 7);     // global gate row
  bf16x8 bfr[16];
#pragma unroll
  for (int ks = 0; ks < 16; ++ks)
    bfr[ks] = *(const bf16x8*)&Whh[(size_t)grow * H_ + ks * 32 + lq * 8];

  // c-state: thread (b=tid>>3, j=tid&7) owns c[b][blk*8+j] in a register.
  const int pb = tid >> 3, pj = tid & 7;
  const int hidx = blk * 8 + pj;
  float c = c0[pb * H_ + hidx];

  __shared__ __align__(16) u16 Hs[32 * 512];  // 32KB: h_{t-1}, all 32 batches
  __shared__ float G[32][33];                 // +1 pad

  const int am = mi * 16 + lr;

  // prefetch gp for t=0
  float gpr[4];
#pragma unroll
  for (int r = 0; r < 4; ++r)
    gpr[r] = gp[(size_t)((mi * 16 + lq * 4 + r) * T_ + 0) * 2048 + grow];

  // stage h0 (Hbuf slot 0) into LDS
#pragma unroll
  for (int it = 0; it < 8; ++it) {
    int chunk = it * 256 + tid;  // 0..2047 16B-chunks
    async_ld16(&Hbuf[chunk * 8], &Hs[chunk * 8]);
  }
  __syncthreads();

  for (int t = 0; t < T_; ++t) {
    f32x4 acc = (f32x4){0.f, 0.f, 0.f, 0.f};
#pragma unroll
    for (int ks = 0; ks < 16; ++ks) {
      bf16x8 a = *(const bf16x8*)&Hs[am * H_ + ks * 32 + lq * 8];
      acc = __builtin_amdgcn_mfma_f32_16x16x32_bf16(a, bfr[ks], acc, 0, 0, 0);
    }
#pragma unroll
    for (int r = 0; r < 4; ++r)
      G[mi * 16 + lq * 4 + r][p] = acc[r] + gpr[r];
    __syncthreads();
    // pointwise: i,f,g,o at cols j, 8+j, 16+j, 24+j of the 32-set
    float gi = G[pb][pj], gf = G[pb][8 + pj], gg = G[pb][16 + pj], go = G[pb][24 + pj];
    c = sigm(gf) * c + sigm(gi) * tanhf(gg);
    float h = sigm(go) * tanhf(c);
    u16 hb = f2b(h);
    Hbuf[(size_t)(t + 1) * (B_ * H_) + pb * H_ + hidx] = hb;
    hc[(size_t)(pb * T_ + t) * 1024 + hidx]            = hb;

    if (t < T_ - 1) {
      // prefetch next step's gp while we wait (constant data: coherence-safe)
#pragma unroll
      for (int r = 0; r < 4; ++r)
        gpr[r] = gp[(size_t)((mi * 16 + lq * 4 + r) * T_ + t + 1) * 2048 + grow];
      __syncthreads();  // drains vmcnt: all block's h stores are in L2
      if (tid == 0) {
        __builtin_amdgcn_fence(__ATOMIC_RELEASE, "agent");  // one wbl2
        __hip_atomic_fetch_add(&bar[t], 1, __ATOMIC_RELAXED, __HIP_MEMORY_SCOPE_AGENT);
        while (__hip_atomic_load(&bar[t], __ATOMIC_RELAXED, __HIP_MEMORY_SCOPE_AGENT) < nblk) {
        }
        __builtin_amdgcn_fence(__ATOMIC_ACQUIRE, "agent");  // one buffer_inv
      }
      __syncthreads();
      // stage h_t into LDS for next iteration
#pragma unroll
      for (int it = 0; it < 8; ++it) {
        int chunk = it * 256 + tid;
        async_ld16(&Hbuf[(size_t)(t + 1) * (B_ * H_) + chunk * 8], &Hs[chunk * 8]);
      }
      __syncthreads();
    }
  }
}

// ---------------------------------------------------------------------------
// Attention: one block per (b,t). scores = q . enc, mask, softmax, ctx.
// enc here is the bf16 copy. Writes ctx (bf16) into hc cols 512..1023.
// ---------------------------------------------------------------------------
__global__ __launch_bounds__(256) void k_attn(
    const u16* __restrict__ q,    // bf16 [B*T][512]
    const u16* __restrict__ enc,  // bf16 [B][S][512]
    const int* __restrict__ lens, // [B]
    u16* __restrict__ hc) {       // bf16 [B*T][1024]
  const int bt = blockIdx.x;
  const int b  = bt >> 6;  // bt = b*T + t
  const int tid = threadIdx.x;
  const int len = lens[b];

  __shared__ float qs[512];
  __shared__ float sc[128];
  __shared__ float red2[256];
  __shared__ float sred[2];

  for (int i = tid; i < 512; i += 256) qs[i] = b2f(q[(size_t)bt * 512 + i]);
  __syncthreads();

  // scores: thread (s = tid&127, half = tid>>7) sums 256 of 512 k's
  {
    int s = tid & 127, half = tid >> 7;
    const u16* er = &enc[((size_t)b * S_ + s) * 512 + half * 256];
    const float* qb = &qs[half * 256];
    float a = 0.f;
#pragma unroll 4
    for (int k = 0; k < 256; k += 8) {
      uint4 raw = *(const uint4*)&er[k];
      u32 w0 = raw.x, w1 = raw.y, w2 = raw.z, w3 = raw.w;
      union { u32 i; float f; } lo, hi;
      lo.i = w0 << 16;          a += lo.f * qb[k + 0];
      hi.i = w0 & 0xffff0000u;  a += hi.f * qb[k + 1];
      lo.i = w1 << 16;          a += lo.f * qb[k + 2];
      hi.i = w1 & 0xffff0000u;  a += hi.f * qb[k + 3];
      lo.i = w2 << 16;          a += lo.f * qb[k + 4];
      hi.i = w2 & 0xffff0000u;  a += hi.f * qb[k + 5];
      lo.i = w3 << 16;          a += lo.f * qb[k + 6];
      hi.i = w3 & 0xffff0000u;  a += hi.f * qb[k + 7];
    }
    red2[tid] = a;
  }
  __syncthreads();
  if (tid < 128) {
    float v = red2[tid] + red2[tid + 128];
    sc[tid] = (tid < len) ? v : -1e30f;
  }
  __syncthreads();
  if (tid < 64) {
    float m = fmaxf(sc[tid], sc[tid + 64]);
#pragma unroll
    for (int o = 32; o > 0; o >>= 1) m = fmaxf(m, __shfl_down(m, o));
    if (tid == 0) sred[0] = m;
  }
  __syncthreads();
  float mx = sred[0];
  if (tid < 128) sc[tid] = __expf(sc[tid] - mx);
  __syncthreads();
  if (tid < 64) {
    float s2 = sc[tid] + sc[tid + 64];
#pragma unroll
    for (int o = 32; o > 0; o >>= 1) s2 += __shfl_down(s2, o);
    if (tid == 0) sred[1] = s2;
  }
  __syncthreads();
  float inv = 1.0f / sred[1];

  // ctx[e] = sum_s att[s] * enc[b][s][e]; thread handles e = tid, tid+256
  float a0 = 0.f, a1 = 0.f;
  for (int s = 0; s < S_; ++s) {
    float at = sc[s];
    const u16* er = &enc[((size_t)b * S_ + s) * 512];
    a0 += at * b2f(er[tid]);
    a1 += at * b2f(er[tid + 256]);
  }
  hc[(size_t)bt * 1024 + 512 + tid]       = f2b(a0 * inv);
  hc[(size_t)bt * 1024 + 512 + tid + 256] = f2b(a1 * inv);
}

// ---------------------------------------------------------------------------
extern "C" void kernel_launch(void* const* d_in, const int* in_sizes, int n_in,
                              void* d_out, int out_size, void* d_ws, size_t ws_size,
                              hipStream_t stream) {
  const int*   toks  = (const int*)d_in[0];
  const float* enc   = (const float*)d_in[1];
  const int*   lens  = (const int*)d_in[2];
  const float* h0    = (const float*)d_in[3];
  const float* c0    = (const float*)d_in[4];
  const float* table = (const float*)d_in[5];
  const float* W_ih  = (const float*)d_in[6];
  const float* W_hh  = (const float*)d_in[7];
  const float* b_ih  = (const float*)d_in[8];
  const float* b_hh  = (const float*)d_in[9];
  const float* Wa    = (const float*)d_in[10];
  const float* Wc_w  = (const float*)d_in[11];
  const float* Wc_b  = (const float*)d_in[12];
  const float* Wo_w  = (const float*)d_in[13];
  const float* Wo_b  = (const float*)d_in[14];
  float* out = (float*)d_out;

  char* ws = (char*)d_ws;
  size_t off = 0;
  auto alloc = [&](size_t bytes) {
    void* pp = ws + off;
    off += (bytes + 255) & ~(size_t)255;
    return pp;
  };
  int*   bar   = (int*)alloc(64 * sizeof(int));
  float* gp    = (float*)alloc((size_t)B_ * T_ * 2048 * 4);    // 16.8 MB
  u16*   emb   = (u16*)alloc((size_t)B_ * T_ * E_ * 2);        // 1 MB
  u16*   Hbuf  = (u16*)alloc((size_t)(T_ + 1) * B_ * H_ * 2);  // 2.1 MB
  u16*   hc    = (u16*)alloc((size_t)B_ * T_ * 1024 * 2);      // 4 MB
  u16*   q     = (u16*)alloc((size_t)B_ * T_ * ENC_ * 2);      // 2 MB
  u16*   WaT   = (u16*)alloc((size_t)ENC_ * H_ * 2);           // 0.5 MB
  u16*   ho    = (u16*)alloc((size_t)B_ * T_ * H_ * 2);        // 2 MB
  u16*   Wihb  = (u16*)alloc((size_t)2048 * E_ * 2);           // 1 MB
  u16*   Whhb  = (u16*)alloc((size_t)2048 * H_ * 2);           // 2 MB
  u16*   Wcwb  = (u16*)alloc((size_t)H_ * 1024 * 2);           // 1 MB
  u16*   Wowb  = (u16*)alloc((size_t)V_ * H_ * 2);             // 32.8 MB
  u16*   encb  = (u16*)alloc((size_t)B_ * S_ * ENC_ * 2);      // 4.2 MB
  (void)in_sizes; (void)n_in; (void)out_size; (void)ws_size;

  hipMemsetAsync(bar, 0, 64 * sizeof(int), stream);

  // 0. dtype converts (f32 -> bf16)
  k_cvt<<<(2048 * E_ / 4 + 255) / 256, 256, 0, stream>>>(W_ih, Wihb, 2048 * E_ / 4);
  k_cvt<<<(2048 * H_ / 4 + 255) / 256, 256, 0, stream>>>(W_hh, Whhb, 2048 * H_ / 4);
  k_cvt<<<(H_ * 1024 / 4 + 255) / 256, 256, 0, stream>>>(Wc_w, Wcwb, H_ * 1024 / 4);
  k_cvt<<<(V_ * H_ / 4 + 255) / 256, 256, 0, stream>>>(Wo_w, Wowb, V_ * H_ / 4);
  k_cvt<<<(B_ * S_ * ENC_ / 4 + 255) / 256, 256, 0, stream>>>(enc, encb, B_ * S_ * ENC_ / 4);
  k_cvt<<<(B_ * H_ / 4 + 255) / 256, 256, 0, stream>>>(h0, Hbuf, B_ * H_ / 4);  // slot 0
  // 1. embedding gather (+convert)
  k_embed<<<512, 256, 0, stream>>>(toks, table, emb);
  // 2. gates_pre = emb @ W_ih^T + b_ih + b_hh   [2048 x 2048], K=256, f32 out
  gemm_bt<float><<<dim3(16, 16), 256, 0, stream>>>(emb, E_, Wihb, E_, gp, 2048, E_, b_ih, b_hh);
  // 3. WaT = Wa^T (bf16)
  k_transpose<<<dim3(16, 16), 256, 0, stream>>>(Wa, WaT);
  // 4. sequential LSTM core -> h into hc[:, 0:512] and Hbuf slots 1..64
  k_lstm<<<64, 256, 0, stream>>>(Whhb, gp, c0, Hbuf, hc, bar);
  // 5. q = h @ Wa  == hc[:,0:512] @ WaT^T   [2048 x 512], K=512, bf16 out
  gemm_bt<u16><<<dim3(16, 4), 256, 0, stream>>>(hc, 1024, WaT, H_, q, ENC_, H_, nullptr, nullptr);
  // 6. attention -> ctx into hc[:, 512:1024]
  k_attn<<<B_ * T_, 256, 0, stream>>>(q, encb, lens, hc);
  // 7. ho = [h,ctx] @ Wc_w^T + Wc_b   [2048 x 512], K=1024
  gemm_bt<u16><<<dim3(16, 4), 256, 0, stream>>>(hc, 1024, Wcwb, 1024, ho, H_, 1024, Wc_b, nullptr);
  // 8. logits = ho @ Wo^T + Wo_b -> d_out (f32)   [2048 x 32000], K=512
  gemm_bt<float><<<dim3(16, 250), 256, 0, stream>>>(ho, H_, Wowb, H_, out, V_, H_, Wo_b, nullptr);
}